// Round 7
// baseline (304.446 us; speedup 1.0000x reference)
//
#include <hip/hip_runtime.h>

#define ALPHA 0.2f

typedef __attribute__((ext_vector_type(8))) short short8;
typedef __attribute__((ext_vector_type(4))) float f32x4;
typedef __attribute__((ext_vector_type(2))) unsigned int u32x2;
typedef __attribute__((ext_vector_type(4))) unsigned int u32x4;

__device__ __forceinline__ short f2bf(float f) {
    unsigned u = __builtin_bit_cast(unsigned, f);
    u += 0x7fffu + ((u >> 16) & 1u);   // RNE
    return (short)(u >> 16);
}
__device__ __forceinline__ unsigned pack2(float a, float b) {
    unsigned ua = __builtin_bit_cast(unsigned, a) + 0x8000u;
    unsigned ub = __builtin_bit_cast(unsigned, b) + 0x8000u;
    return (ua >> 16) | (ub & 0xffff0000u);
}
__device__ __forceinline__ float bf2f(short s) {
    return __builtin_bit_cast(float, ((unsigned)(unsigned short)s) << 16);
}
__device__ __forceinline__ float lrelu(float v) { return fmaxf(v, ALPHA * v); }

// ---- weight prep ----
__global__ void prep_kernel(const float* __restrict__ feW0, const float* __restrict__ feW1,
                            const float* __restrict__ feW2, const float* __restrict__ fnW0,
                            const float* __restrict__ fnW1,
                            short* __restrict__ W1F, short* __restrict__ W2F,
                            short* __restrict__ W0uvF,
                            short* __restrict__ Wn0T, short* __restrict__ Wn1T)
{
    const int tid = blockIdx.x * blockDim.x + threadIdx.x;
    const int T = gridDim.x * blockDim.x;
    // W1F fragment-linear: idx=((mt*8+ks)*64+lane)*8+e ; feat=mt*16+(lane&15); k=ks*32+(lane>>4)*8+e
    for (int t = tid; t < 65536; t += T) {
        int e = t & 7, lane = (t >> 3) & 63, ks = (t >> 9) & 7, mt = t >> 12;
        int feat = mt * 16 + (lane & 15), k = ks * 32 + (lane >> 4) * 8 + e;
        W1F[t] = f2bf(feW1[k * 256 + feat]);
    }
    // W2F: 128 feats (>=96 zero) x 256 k
    for (int t = tid; t < 32768; t += T) {
        int e = t & 7, lane = (t >> 3) & 63, ks = (t >> 9) & 7, mt = t >> 12;
        int feat = mt * 16 + (lane & 15), k = ks * 32 + (lane >> 4) * 8 + e;
        W2F[t] = f2bf(feat < 96 ? feW2[k * 96 + feat] : 0.f);
    }
    // W0uvF: 512 feats x 64 k; feat<256 -> W0a col, else W0b col
    for (int t = tid; t < 32768; t += T) {
        int e = t & 7, lane = (t >> 3) & 63, ks = (t >> 9) & 1, mt = t >> 10;
        int feat = mt * 16 + (lane & 15), k = ks * 32 + (lane >> 4) * 8 + e;
        float val = (feat < 256) ? feW0[k * 256 + feat] : feW0[(64 + k) * 256 + (feat - 256)];
        W0uvF[t] = f2bf(val);
    }
    for (int t = tid; t < 256 * 160; t += T) { int n = t / 160, k = t - n * 160; Wn0T[t] = f2bf(fnW0[k * 256 + n]); }
    for (int t = tid; t < 64 * 256; t += T) { int n = t >> 8, k = t & 255; Wn1T[t] = f2bf(fnW1[k * 64 + n]); }
}

// ---- u,v precompute ----
__global__ __launch_bounds__(256, 4)
void uv_kernel(const float* __restrict__ x, const short* __restrict__ W0uvF,
               float* __restrict__ u, float* __restrict__ v)
{
    __shared__ __align__(16) short xb[4096];
    const int tid = threadIdx.x;
    const int lane = tid & 63, wid = tid >> 6;
    const int l15 = lane & 15, lg = lane >> 4;
    const int r0 = blockIdx.x * 64;

    for (int t = tid; t < 4096; t += 256) {
        int row = t >> 6;
        int byte = (t * 2) ^ ((row & 7) << 4);
        *(short*)((char*)xb + byte) = f2bf(x[r0 * 64 + t]);
    }
    __syncthreads();

    #pragma unroll
    for (int pair = 0; pair < 4; ++pair) {
        const int mt0 = wid * 8 + pair * 2;
        f32x4 acc[2][4];
        #pragma unroll
        for (int m = 0; m < 2; ++m)
            #pragma unroll
            for (int nt = 0; nt < 4; ++nt) acc[m][nt] = (f32x4){0.f, 0.f, 0.f, 0.f};
        #pragma unroll
        for (int ks = 0; ks < 2; ++ks) {
            short8 a[2], bf[4];
            #pragma unroll
            for (int m = 0; m < 2; ++m)
                a[m] = *(const short8*)&W0uvF[(((mt0 + m) * 2 + ks) * 64 + lane) * 8];
            #pragma unroll
            for (int nt = 0; nt < 4; ++nt) {
                int row = nt * 16 + l15;
                int byte = (row * 128 + (ks * 32 + lg * 8) * 2) ^ ((row & 7) << 4);
                bf[nt] = *(const short8*)((char*)xb + byte);
            }
            #pragma unroll
            for (int m = 0; m < 2; ++m)
                #pragma unroll
                for (int nt = 0; nt < 4; ++nt)
                    acc[m][nt] = __builtin_amdgcn_mfma_f32_16x16x32_bf16(a[m], bf[nt], acc[m][nt], 0, 0, 0);
        }
        #pragma unroll
        for (int m = 0; m < 2; ++m) {
            int feat0 = (mt0 + m) * 16 + lg * 4;
            #pragma unroll
            for (int nt = 0; nt < 4; ++nt) {
                int R = r0 + nt * 16 + l15;
                float* dst = (feat0 < 256) ? &u[R * 256 + feat0] : &v[R * 256 + (feat0 - 256)];
                *(f32x4*)dst = acc[m][nt];
            }
        }
    }
}

// ---- edge MLP + aggregation: one block per (b, 16-i group); 1024 threads, 16 waves.
// NOTE launch_bounds 2nd arg behaves as min BLOCKS/CU on this toolchain (measured
// R2/R3/R4/R5): (1024,1) => 16 waves/CU => 4 waves/SIMD => VGPR cap 128.
__global__ __launch_bounds__(1024, 1)
void edge_kernel(const float* __restrict__ x, const float* __restrict__ feW0,
                 const float* __restrict__ b0v, const float* __restrict__ b1v,
                 const float* __restrict__ b2v,
                 const short* __restrict__ W1F, const short* __restrict__ W2F,
                 const float* __restrict__ u, const float* __restrict__ v,
                 float* __restrict__ agg)
{
    __shared__ __align__(16) char smem[122368];
    char* vb = smem;                         // bf16 [64][256] swz     (32768)
    char* h0 = smem + 32768;                 // bf16 [64][256] swz     (32768)
    char* h1 = smem + 65536;                 // bf16 [64][256] swz     (32768)
    float* ub_f = (float*)(smem + 98304);    // f32 [16][256]          (16384)
    float* wd_f = (float*)(smem + 114688);   // f32 [256]              (1024)
    float* dist = (float*)(smem + 115712);   // f32 [16][64]           (4096)
    float* part = (float*)(smem + 119808);   // f32 [2][128]           (1024)
    float* bb1s = (float*)(smem + 120832);   // f32 [256]              (1024)
    float* bb2s = (float*)(smem + 121856);   // f32 [128]              (512)
    float* xs   = (float*)(smem + 65536);    // alias h1: f32 [64][68] (17408)

    const int tid = threadIdx.x;
    const int lane = tid & 63, wid = tid >> 6;     // wid 0..15
    const int l15 = lane & 15, lg = lane >> 4;
    const int fw = wid & 7, jh = wid >> 3;         // feat-slice, j-half
    const int jr = tid >> 4, cb = (tid & 15) * 16; // BUILD row / col-base
    const int b = blockIdx.x >> 2, i0 = (blockIdx.x & 3) * 16;

    // ---- weight fragments -> registers (96 VGPR persistent) ----
    short8 a1[2][8];   // W1 feats [fw*32, fw*32+32)
    #pragma unroll
    for (int m = 0; m < 2; ++m)
        #pragma unroll
        for (int ks = 0; ks < 8; ++ks)
            a1[m][ks] = *(const short8*)&W1F[(((fw * 2 + m) * 8 + ks) * 64 + lane) * 8];
    short8 a2[8];      // W2 feats [fw*16, fw*16+16) of 128-pad
    #pragma unroll
    for (int ks = 0; ks < 8; ++ks)
        a2[ks] = *(const short8*)&W2F[((fw * 8 + ks) * 64 + lane) * 8];

    // ---- prologue staging ----
    {   // xs: x[b] f32 [64][68]
        const float* xb = x + b * 4096;
        *(f32x4*)&xs[jr * 68 + (tid & 15) * 4] = *(const f32x4*)&xb[jr * 64 + (tid & 15) * 4];
    }
    {   // vb: v[b] -> bf16 swizzled
        const float* gv = v + (b * 64 + jr) * 256 + cb;
        f32x4 v0 = *(const f32x4*)&gv[0];
        f32x4 v1 = *(const f32x4*)&gv[4];
        f32x4 v2 = *(const f32x4*)&gv[8];
        f32x4 v3 = *(const f32x4*)&gv[12];
        u32x4 p0, p1;
        p0[0] = pack2(v0[0], v0[1]); p0[1] = pack2(v0[2], v0[3]);
        p0[2] = pack2(v1[0], v1[1]); p0[3] = pack2(v1[2], v1[3]);
        p1[0] = pack2(v2[0], v2[1]); p1[1] = pack2(v2[2], v2[3]);
        p1[2] = pack2(v3[0], v3[1]); p1[3] = pack2(v3[2], v3[3]);
        int swz = (jr & 7) << 4;
        *(u32x4*)(vb + ((jr * 512 + cb * 2) ^ swz)) = p0;
        *(u32x4*)(vb + ((jr * 512 + cb * 2 + 16) ^ swz)) = p1;
    }
    {   // ub: u[b, i0+ii] + b0
        int ii = tid >> 6, c0 = (tid & 63) * 4;
        f32x4 uu = *(const f32x4*)&u[(b * 64 + i0 + ii) * 256 + c0];
        uu += *(const f32x4*)&b0v[c0];
        *(f32x4*)&ub_f[ii * 256 + c0] = uu;
    }
    if (tid < 64) {
        f32x4 w0 = *(const f32x4*)&feW0[128 * 256 + tid * 4];
        *(f32x4*)&wd_f[tid * 4] = w0;
    }
    if (tid < 256) bb1s[tid] = b1v[tid];
    else if (tid < 384) bb2s[tid - 256] = ((tid - 256) < 96) ? b2v[tid - 256] : 0.f;
    __syncthreads();

    // ---- dist[ii][j] ----
    {
        f32x4 xj = *(const f32x4*)&xs[jr * 68 + (tid & 15) * 4];
        #pragma unroll
        for (int ii = 0; ii < 16; ++ii) {
            f32x4 xi = *(const f32x4*)&xs[(i0 + ii) * 68 + (tid & 15) * 4];
            float ss = 0.f;
            #pragma unroll
            for (int r = 0; r < 4; ++r) {
                float d = xj[r] - xi[r] + 1e-12f;
                ss += d * d;
            }
            ss += __shfl_xor(ss, 1); ss += __shfl_xor(ss, 2);
            ss += __shfl_xor(ss, 4); ss += __shfl_xor(ss, 8);
            if ((tid & 15) == 0) dist[ii * 64 + jr] = sqrtf(ss);
        }
    }
    __syncthreads();

    // build h0 rows for node i = i0+ii_ ; thread: row jr, cols [cb, cb+16)
    #define BUILD(ii_) do { \
        float dj = dist[(ii_) * 64 + jr]; \
        _Pragma("unroll") \
        for (int e = 0; e < 2; ++e) { \
            int c0 = cb + e * 8; \
            int byte = (jr * 512 + c0 * 2) ^ ((jr & 7) << 4); \
            short8 vr = *(const short8*)(vb + byte); \
            f32x4 uu0 = *(const f32x4*)&ub_f[(ii_) * 256 + c0]; \
            f32x4 uu1 = *(const f32x4*)&ub_f[(ii_) * 256 + c0 + 4]; \
            f32x4 ww0 = *(const f32x4*)&wd_f[c0]; \
            f32x4 ww1 = *(const f32x4*)&wd_f[c0 + 4]; \
            float t0 = lrelu(uu0[0] + bf2f(vr[0]) + dj * ww0[0]); \
            float t1 = lrelu(uu0[1] + bf2f(vr[1]) + dj * ww0[1]); \
            float t2 = lrelu(uu0[2] + bf2f(vr[2]) + dj * ww0[2]); \
            float t3 = lrelu(uu0[3] + bf2f(vr[3]) + dj * ww0[3]); \
            float t4 = lrelu(uu1[0] + bf2f(vr[4]) + dj * ww1[0]); \
            float t5 = lrelu(uu1[1] + bf2f(vr[5]) + dj * ww1[1]); \
            float t6 = lrelu(uu1[2] + bf2f(vr[6]) + dj * ww1[2]); \
            float t7 = lrelu(uu1[3] + bf2f(vr[7]) + dj * ww1[3]); \
            u32x4 pk; \
            pk[0] = pack2(t0, t1); pk[1] = pack2(t2, t3); \
            pk[2] = pack2(t4, t5); pk[3] = pack2(t6, t7); \
            *(u32x4*)(h0 + byte) = pk; \
        } \
    } while (0)

    BUILD(0);
    __syncthreads();

    float* aggrow = agg + (b * 64 + i0) * 96;
    for (int ii = 0; ii < 16; ++ii) {
        // ---- phase A: flush agg(ii-1) + GEMM1: h1 = lrelu(W1 @ h0 + b1) ----
        if (ii > 0 && tid < 96)
            aggrow[(ii - 1) * 96 + tid] = part[tid] + part[128 + tid];
        {
            f32x4 acc[2][2];
            acc[0][0] = (f32x4){0.f,0.f,0.f,0.f}; acc[0][1] = (f32x4){0.f,0.f,0.f,0.f};
            acc[1][0] = (f32x4){0.f,0.f,0.f,0.f}; acc[1][1] = (f32x4){0.f,0.f,0.f,0.f};
            #pragma unroll
            for (int ks = 0; ks < 8; ++ks) {
                short8 bfr[2];
                #pragma unroll
                for (int nt = 0; nt < 2; ++nt) {
                    int j = jh * 32 + nt * 16 + l15;
                    bfr[nt] = *(const short8*)(h0 + ((j * 512 + (ks * 32 + lg * 8) * 2) ^ ((j & 7) << 4)));
                }
                #pragma unroll
                for (int m = 0; m < 2; ++m)
                    #pragma unroll
                    for (int nt = 0; nt < 2; ++nt)
                        acc[m][nt] = __builtin_amdgcn_mfma_f32_16x16x32_bf16(a1[m][ks], bfr[nt], acc[m][nt], 0, 0, 0);
            }
            #pragma unroll
            for (int m = 0; m < 2; ++m) {
                int f0 = fw * 32 + m * 16 + lg * 4;
                f32x4 bb = *(const f32x4*)&bb1s[f0];
                #pragma unroll
                for (int nt = 0; nt < 2; ++nt) {
                    int j = jh * 32 + nt * 16 + l15;
                    float q0 = lrelu(acc[m][nt][0] + bb[0]);
                    float q1 = lrelu(acc[m][nt][1] + bb[1]);
                    float q2 = lrelu(acc[m][nt][2] + bb[2]);
                    float q3 = lrelu(acc[m][nt][3] + bb[3]);
                    u32x2 pv; pv[0] = pack2(q0, q1); pv[1] = pack2(q2, q3);
                    *(u32x2*)(h1 + ((j * 512 + f0 * 2) ^ ((j & 7) << 4))) = pv;
                }
            }
        }
        __syncthreads();
        // ---- phase B: GEMM2 + j-half aggregate -> part; then BUILD(ii+1) ----
        {
            f32x4 acc2[2];
            acc2[0] = (f32x4){0.f,0.f,0.f,0.f}; acc2[1] = (f32x4){0.f,0.f,0.f,0.f};
            #pragma unroll
            for (int ks = 0; ks < 8; ++ks) {
                #pragma unroll
                for (int nt = 0; nt < 2; ++nt) {
                    int j = jh * 32 + nt * 16 + l15;
                    short8 bfr = *(const short8*)(h1 + ((j * 512 + (ks * 32 + lg * 8) * 2) ^ ((j & 7) << 4)));
                    acc2[nt] = __builtin_amdgcn_mfma_f32_16x16x32_bf16(a2[ks], bfr, acc2[nt], 0, 0, 0);
                }
            }
            f32x4 bb = *(const f32x4*)&bb2s[fw * 16 + lg * 4];
            f32x4 s;
            #pragma unroll
            for (int r = 0; r < 4; ++r)
                s[r] = lrelu(acc2[0][r] + bb[r]) + lrelu(acc2[1][r] + bb[r]);
            #pragma unroll
            for (int r = 0; r < 4; ++r) {
                float t = s[r];
                t += __shfl_xor(t, 1); t += __shfl_xor(t, 2);
                t += __shfl_xor(t, 4); t += __shfl_xor(t, 8);
                s[r] = t;
            }
            if (l15 == 0) *(f32x4*)&part[jh * 128 + fw * 16 + lg * 4] = s;
        }
        __builtin_amdgcn_sched_barrier(0);
        if (ii < 15) BUILD(ii + 1);
        __syncthreads();
    }
    if (tid < 96)
        aggrow[15 * 96 + tid] = part[tid] + part[128 + tid];
    #undef BUILD
}

// ---- node MLP ----
__global__ __launch_bounds__(256, 2)
void node_kernel(const float* __restrict__ x, const float* __restrict__ agg,
                 const short* __restrict__ Wn0T, const short* __restrict__ Wn1T,
                 const float* __restrict__ bn0, const float* __restrict__ bn1,
                 float* __restrict__ out)
{
    __shared__ short A2[64 * 168];
    __shared__ short H[64 * 264];
    const int tid = threadIdx.x;
    const int lane = tid & 63, wid = tid >> 6;
    const int l15 = lane & 15, lg = lane >> 4;
    const int r0 = blockIdx.x * 64;

    for (int t = tid; t < 64 * 160; t += 256) {
        int j = t / 160, c = t - j * 160;
        float vv = (c < 96) ? agg[(r0 + j) * 96 + c] : x[(r0 + j) * 64 + (c - 96)];
        A2[j * 168 + c] = f2bf(vv);
    }
    __syncthreads();

    {
        f32x4 acc[4][4];
        #pragma unroll
        for (int mt = 0; mt < 4; ++mt)
            #pragma unroll
            for (int nt = 0; nt < 4; ++nt) acc[mt][nt] = (f32x4){0.f, 0.f, 0.f, 0.f};
        const int n0 = wid * 64;
        #pragma unroll
        for (int ks = 0; ks < 5; ++ks) {
            const int k0 = ks * 32 + lg * 8;
            short8 a[4], bf[4];
            #pragma unroll
            for (int mt = 0; mt < 4; ++mt)
                a[mt] = *reinterpret_cast<const short8*>(&A2[(mt * 16 + l15) * 168 + k0]);
            #pragma unroll
            for (int nt = 0; nt < 4; ++nt)
                bf[nt] = *reinterpret_cast<const short8*>(&Wn0T[(n0 + nt * 16 + l15) * 160 + k0]);
            #pragma unroll
            for (int mt = 0; mt < 4; ++mt)
                #pragma unroll
                for (int nt = 0; nt < 4; ++nt)
                    acc[mt][nt] = __builtin_amdgcn_mfma_f32_16x16x32_bf16(a[mt], bf[nt], acc[mt][nt], 0, 0, 0);
        }
        #pragma unroll
        for (int nt = 0; nt < 4; ++nt) {
            const int col = n0 + nt * 16 + l15;
            const float bv = bn0[col];
            #pragma unroll
            for (int mt = 0; mt < 4; ++mt)
                #pragma unroll
                for (int r = 0; r < 4; ++r)
                    H[(mt * 16 + lg * 4 + r) * 264 + col] = f2bf(lrelu(acc[mt][nt][r] + bv));
        }
    }
    __syncthreads();

    {
        f32x4 acc[4];
        #pragma unroll
        for (int mt = 0; mt < 4; ++mt) acc[mt] = (f32x4){0.f, 0.f, 0.f, 0.f};
        #pragma unroll
        for (int ks = 0; ks < 8; ++ks) {
            const int k0 = ks * 32 + lg * 8;
            short8 bf = *reinterpret_cast<const short8*>(&Wn1T[(wid * 16 + l15) * 256 + k0]);
            #pragma unroll
            for (int mt = 0; mt < 4; ++mt) {
                short8 a = *reinterpret_cast<const short8*>(&H[(mt * 16 + l15) * 264 + k0]);
                acc[mt] = __builtin_amdgcn_mfma_f32_16x16x32_bf16(a, bf, acc[mt], 0, 0, 0);
            }
        }
        const int col = wid * 16 + l15;
        const float bv = bn1[col];
        #pragma unroll
        for (int mt = 0; mt < 4; ++mt)
            #pragma unroll
            for (int r = 0; r < 4; ++r)
                out[(r0 + mt * 16 + lg * 4 + r) * 64 + col] = acc[mt][r] + bv;
    }
}

extern "C" void kernel_launch(void* const* d_in, const int* in_sizes, int n_in,
                              void* d_out, int out_size, void* d_ws, size_t ws_size,
                              hipStream_t stream) {
    (void)in_sizes; (void)n_in; (void)out_size; (void)ws_size;
    const float* x    = (const float*)d_in[0];
    const float* feW0 = (const float*)d_in[1];
    const float* feb0 = (const float*)d_in[2];
    const float* feW1 = (const float*)d_in[3];
    const float* feb1 = (const float*)d_in[4];
    const float* feW2 = (const float*)d_in[5];
    const float* feb2 = (const float*)d_in[6];
    const float* fnW0 = (const float*)d_in[7];
    const float* fnb0 = (const float*)d_in[8];
    const float* fnW1 = (const float*)d_in[9];
    const float* fnb1 = (const float*)d_in[10];

    char* ws = (char*)d_ws;
    short* W1F   = (short*)(ws + 0);          // 131072
    short* W2F   = (short*)(ws + 131072);     // 65536
    short* W0uvF = (short*)(ws + 196608);     // 65536
    short* Wn0T  = (short*)(ws + 262144);     // 81920
    short* Wn1T  = (short*)(ws + 344064);     // 32768
    float* agg   = (float*)(ws + 376832);     // 3145728
    float* u     = (float*)(ws + 3522560);    // 8388608
    float* v     = (float*)(ws + 11911168);   // 8388608

    hipLaunchKernelGGL(prep_kernel, dim3(64), dim3(256), 0, stream,
                       feW0, feW1, feW2, fnW0, fnW1, W1F, W2F, W0uvF, Wn0T, Wn1T);
    hipLaunchKernelGGL(uv_kernel, dim3(128), dim3(256), 0, stream,
                       x, W0uvF, u, v);
    hipLaunchKernelGGL(edge_kernel, dim3(512), dim3(1024), 0, stream,
                       x, feW0, feb0, feb1, feb2, W1F, W2F, u, v, agg);
    hipLaunchKernelGGL(node_kernel, dim3(128), dim3(256), 0, stream,
                       x, agg, Wn0T, Wn1T, fnb0, fnb1, (float*)d_out);
}

// Round 8
// 197.976 us; speedup vs baseline: 1.5378x; 1.5378x over previous
//
#include <hip/hip_runtime.h>

#define ALPHA 0.2f

typedef __attribute__((ext_vector_type(8))) short short8;
typedef __attribute__((ext_vector_type(4))) float f32x4;
typedef __attribute__((ext_vector_type(2))) unsigned int u32x2;
typedef __attribute__((ext_vector_type(4))) unsigned int u32x4;

__device__ __forceinline__ short f2bf(float f) {
    unsigned u = __builtin_bit_cast(unsigned, f);
    u += 0x7fffu + ((u >> 16) & 1u);   // RNE
    return (short)(u >> 16);
}
__device__ __forceinline__ unsigned pack2(float a, float b) {
    unsigned ua = __builtin_bit_cast(unsigned, a) + 0x8000u;
    unsigned ub = __builtin_bit_cast(unsigned, b) + 0x8000u;
    return (ua >> 16) | (ub & 0xffff0000u);
}
__device__ __forceinline__ float bf2f(short s) {
    return __builtin_bit_cast(float, ((unsigned)(unsigned short)s) << 16);
}
__device__ __forceinline__ float lrelu(float v) { return fmaxf(v, ALPHA * v); }

// ---- weight prep ----
__global__ void prep_kernel(const float* __restrict__ feW0, const float* __restrict__ feW1,
                            const float* __restrict__ feW2, const float* __restrict__ fnW0,
                            const float* __restrict__ fnW1,
                            short* __restrict__ W1F, short* __restrict__ W2F,
                            short* __restrict__ W0uvF,
                            short* __restrict__ Wn0T, short* __restrict__ Wn1T)
{
    const int tid = blockIdx.x * blockDim.x + threadIdx.x;
    const int T = gridDim.x * blockDim.x;
    // W1F fragment-linear: idx=((mt*8+ks)*64+lane)*8+e ; feat=mt*16+(lane&15); k=ks*32+(lane>>4)*8+e
    for (int t = tid; t < 65536; t += T) {
        int e = t & 7, lane = (t >> 3) & 63, ks = (t >> 9) & 7, mt = t >> 12;
        int feat = mt * 16 + (lane & 15), k = ks * 32 + (lane >> 4) * 8 + e;
        W1F[t] = f2bf(feW1[k * 256 + feat]);
    }
    // W2F: 128 feats (>=96 zero) x 256 k
    for (int t = tid; t < 32768; t += T) {
        int e = t & 7, lane = (t >> 3) & 63, ks = (t >> 9) & 7, mt = t >> 12;
        int feat = mt * 16 + (lane & 15), k = ks * 32 + (lane >> 4) * 8 + e;
        W2F[t] = f2bf(feat < 96 ? feW2[k * 96 + feat] : 0.f);
    }
    // W0uvF: 512 feats x 64 k; feat<256 -> W0a col, else W0b col
    for (int t = tid; t < 32768; t += T) {
        int e = t & 7, lane = (t >> 3) & 63, ks = (t >> 9) & 1, mt = t >> 10;
        int feat = mt * 16 + (lane & 15), k = ks * 32 + (lane >> 4) * 8 + e;
        float val = (feat < 256) ? feW0[k * 256 + feat] : feW0[(64 + k) * 256 + (feat - 256)];
        W0uvF[t] = f2bf(val);
    }
    for (int t = tid; t < 256 * 160; t += T) { int n = t / 160, k = t - n * 160; Wn0T[t] = f2bf(fnW0[k * 256 + n]); }
    for (int t = tid; t < 64 * 256; t += T) { int n = t >> 8, k = t & 255; Wn1T[t] = f2bf(fnW1[k * 64 + n]); }
}

// ---- u,v precompute ----
__global__ __launch_bounds__(256, 4)
void uv_kernel(const float* __restrict__ x, const short* __restrict__ W0uvF,
               float* __restrict__ u, float* __restrict__ v)
{
    __shared__ __align__(16) short xb[4096];
    const int tid = threadIdx.x;
    const int lane = tid & 63, wid = tid >> 6;
    const int l15 = lane & 15, lg = lane >> 4;
    const int r0 = blockIdx.x * 64;

    for (int t = tid; t < 4096; t += 256) {
        int row = t >> 6;
        int byte = (t * 2) ^ ((row & 7) << 4);
        *(short*)((char*)xb + byte) = f2bf(x[r0 * 64 + t]);
    }
    __syncthreads();

    #pragma unroll
    for (int pair = 0; pair < 4; ++pair) {
        const int mt0 = wid * 8 + pair * 2;
        f32x4 acc[2][4];
        #pragma unroll
        for (int m = 0; m < 2; ++m)
            #pragma unroll
            for (int nt = 0; nt < 4; ++nt) acc[m][nt] = (f32x4){0.f, 0.f, 0.f, 0.f};
        #pragma unroll
        for (int ks = 0; ks < 2; ++ks) {
            short8 a[2], bf[4];
            #pragma unroll
            for (int m = 0; m < 2; ++m)
                a[m] = *(const short8*)&W0uvF[(((mt0 + m) * 2 + ks) * 64 + lane) * 8];
            #pragma unroll
            for (int nt = 0; nt < 4; ++nt) {
                int row = nt * 16 + l15;
                int byte = (row * 128 + (ks * 32 + lg * 8) * 2) ^ ((row & 7) << 4);
                bf[nt] = *(const short8*)((char*)xb + byte);
            }
            #pragma unroll
            for (int m = 0; m < 2; ++m)
                #pragma unroll
                for (int nt = 0; nt < 4; ++nt)
                    acc[m][nt] = __builtin_amdgcn_mfma_f32_16x16x32_bf16(a[m], bf[nt], acc[m][nt], 0, 0, 0);
        }
        #pragma unroll
        for (int m = 0; m < 2; ++m) {
            int feat0 = (mt0 + m) * 16 + lg * 4;
            #pragma unroll
            for (int nt = 0; nt < 4; ++nt) {
                int R = r0 + nt * 16 + l15;
                float* dst = (feat0 < 256) ? &u[R * 256 + feat0] : &v[R * 256 + (feat0 - 256)];
                *(f32x4*)dst = acc[m][nt];
            }
        }
    }
}

// ---- edge MLP + aggregation: one block per (b, 16-i group); 512 threads, 8 waves.
// LDS trimmed to 80384 B so 2 blocks/CU fit (16 waves/CU, 4/SIMD, VGPR cap 128 —
// R2-proven budget ~120). v is read from global/L2 inside BUILD (no vb staging).
__global__ __launch_bounds__(512, 2)
void edge_kernel(const float* __restrict__ x, const float* __restrict__ feW0,
                 const float* __restrict__ b0v, const float* __restrict__ b1v,
                 const float* __restrict__ b2v,
                 const short* __restrict__ W1F, const short* __restrict__ W2F,
                 const float* __restrict__ u, const float* __restrict__ v,
                 float* __restrict__ agg)
{
    __shared__ __align__(16) char smem[80384];
    char* h0 = smem;                          // bf16 [64][256] swz    (32768)
    char* h1 = smem + 32768;                  // bf16 [64][256] swz    (32768)
    short* ub_b = (short*)(smem + 65536);     // bf16 [16][256]        (8192)
    float* wd_f = (float*)(smem + 73728);     // f32 [256]             (1024)
    float* dist = (float*)(smem + 74752);     // f32 [16][64]          (4096)
    float* bb1s = (float*)(smem + 78848);     // f32 [256]             (1024)
    float* bb2s = (float*)(smem + 79872);     // f32 [128]             (512)
    float* xs   = (float*)(smem + 32768);     // alias h1: f32 [64][68] (17408), prologue only

    const int tid = threadIdx.x;
    const int lane = tid & 63, wid = tid >> 6;
    const int l15 = lane & 15, lg = lane >> 4;
    const int j8 = tid >> 3, p8 = tid & 7;
    const int b = blockIdx.x >> 2, i0 = (blockIdx.x & 3) * 16;
    const float* vbase = v + (size_t)b * 64 * 256;

    // ---- weight fragments -> registers (96 VGPR persistent, R2-proven) ----
    short8 a1[2][8];   // W1 feats [wid*32, wid*32+32)
    #pragma unroll
    for (int m = 0; m < 2; ++m)
        #pragma unroll
        for (int ks = 0; ks < 8; ++ks)
            a1[m][ks] = *(const short8*)&W1F[(((wid * 2 + m) * 8 + ks) * 64 + lane) * 8];
    short8 a2[8];      // W2 feats [wid*16, wid*16+16), valid for wid<6
    #pragma unroll
    for (int ks = 0; ks < 8; ++ks)
        a2[ks] = *(const short8*)&W2F[((min(wid, 5) * 8 + ks) * 64 + lane) * 8];

    // ---- prologue staging ----
    {   // xs: x[b] f32 [64][68]
        const float* xb = x + b * 4096;
        *(f32x4*)&xs[j8 * 68 + p8 * 8]     = *(const f32x4*)&xb[j8 * 64 + p8 * 8];
        *(f32x4*)&xs[j8 * 68 + p8 * 8 + 4] = *(const f32x4*)&xb[j8 * 64 + p8 * 8 + 4];
    }
    {   // ub: bf16(u[b, i0+ii] + b0)
        int ii = tid >> 5, c0 = (tid & 31) * 8;
        f32x4 u0 = *(const f32x4*)&u[(b * 64 + i0 + ii) * 256 + c0];
        f32x4 u1 = *(const f32x4*)&u[(b * 64 + i0 + ii) * 256 + c0 + 4];
        u0 += *(const f32x4*)&b0v[c0];
        u1 += *(const f32x4*)&b0v[c0 + 4];
        u32x4 pk;
        pk[0] = pack2(u0[0], u0[1]); pk[1] = pack2(u0[2], u0[3]);
        pk[2] = pack2(u1[0], u1[1]); pk[3] = pack2(u1[2], u1[3]);
        *(u32x4*)&ub_b[ii * 256 + c0] = pk;
    }
    if (tid < 64) {
        f32x4 w0 = *(const f32x4*)&feW0[128 * 256 + tid * 4];
        *(f32x4*)&wd_f[tid * 4] = w0;
    }
    if (tid < 256) bb1s[tid] = b1v[tid];
    else if (tid < 352) bb2s[tid - 256] = b2v[tid - 256];
    __syncthreads();

    // ---- dist[ii][j] ----
    {
        f32x4 xj0 = *(const f32x4*)&xs[j8 * 68 + p8 * 8];
        f32x4 xj1 = *(const f32x4*)&xs[j8 * 68 + p8 * 8 + 4];
        #pragma unroll
        for (int ii = 0; ii < 16; ++ii) {
            const float* xi = &xs[(i0 + ii) * 68 + p8 * 8];
            f32x4 xi0 = *(const f32x4*)&xi[0];
            f32x4 xi1 = *(const f32x4*)&xi[4];
            float ss = 0.f;
            #pragma unroll
            for (int r = 0; r < 4; ++r) {
                float d0 = xj0[r] - xi0[r] + 1e-12f;
                float d1 = xj1[r] - xi1[r] + 1e-12f;
                ss += d0 * d0 + d1 * d1;
            }
            ss += __shfl_xor(ss, 1); ss += __shfl_xor(ss, 2); ss += __shfl_xor(ss, 4);
            if (p8 == 0) dist[ii * 64 + j8] = sqrtf(ss);
        }
    }
    __syncthreads();

    // build h0 rows for node i = i0+ii_ ; thread: row j8, cols [p8*32, p8*32+32);
    // v comes from global (L1/L2-resident), ub from LDS bf16, wd from LDS f32.
    #define BUILD(ii_) do { \
        float dj = dist[(ii_) * 64 + j8]; \
        const float* gv = vbase + j8 * 256 + p8 * 32; \
        _Pragma("unroll") \
        for (int e = 0; e < 4; ++e) { \
            int c0 = p8 * 32 + e * 8; \
            f32x4 va = *(const f32x4*)&gv[e * 8]; \
            f32x4 vb4 = *(const f32x4*)&gv[e * 8 + 4]; \
            short8 ur = *(const short8*)&ub_b[(ii_) * 256 + c0]; \
            f32x4 ww0 = *(const f32x4*)&wd_f[c0]; \
            f32x4 ww1 = *(const f32x4*)&wd_f[c0 + 4]; \
            float t0 = lrelu(bf2f(ur[0]) + va[0] + dj * ww0[0]); \
            float t1 = lrelu(bf2f(ur[1]) + va[1] + dj * ww0[1]); \
            float t2 = lrelu(bf2f(ur[2]) + va[2] + dj * ww0[2]); \
            float t3 = lrelu(bf2f(ur[3]) + va[3] + dj * ww0[3]); \
            float t4 = lrelu(bf2f(ur[4]) + vb4[0] + dj * ww1[0]); \
            float t5 = lrelu(bf2f(ur[5]) + vb4[1] + dj * ww1[1]); \
            float t6 = lrelu(bf2f(ur[6]) + vb4[2] + dj * ww1[2]); \
            float t7 = lrelu(bf2f(ur[7]) + vb4[3] + dj * ww1[3]); \
            u32x4 pk; \
            pk[0] = pack2(t0, t1); pk[1] = pack2(t2, t3); \
            pk[2] = pack2(t4, t5); pk[3] = pack2(t6, t7); \
            *(u32x4*)(h0 + ((j8 * 512 + c0 * 2) ^ ((j8 & 7) << 4))) = pk; \
        } \
    } while (0)

    BUILD(0);
    __syncthreads();

    float* aggrow = agg + (b * 64 + i0) * 96;
    for (int ii = 0; ii < 16; ++ii) {
        // ---- phase A: GEMM1  h1 = lrelu(W1 @ h0 + b1) ----
        {
            f32x4 acc[2][4];
            #pragma unroll
            for (int m = 0; m < 2; ++m)
                #pragma unroll
                for (int nt = 0; nt < 4; ++nt) acc[m][nt] = (f32x4){0.f, 0.f, 0.f, 0.f};
            #pragma unroll
            for (int ks = 0; ks < 8; ++ks) {
                short8 bfr[4];
                #pragma unroll
                for (int nt = 0; nt < 4; ++nt) {
                    int j = nt * 16 + l15;
                    bfr[nt] = *(const short8*)(h0 + ((j * 512 + (ks * 32 + lg * 8) * 2) ^ ((j & 7) << 4)));
                }
                #pragma unroll
                for (int m = 0; m < 2; ++m)
                    #pragma unroll
                    for (int nt = 0; nt < 4; ++nt)
                        acc[m][nt] = __builtin_amdgcn_mfma_f32_16x16x32_bf16(a1[m][ks], bfr[nt], acc[m][nt], 0, 0, 0);
            }
            #pragma unroll
            for (int m = 0; m < 2; ++m) {
                int f0 = wid * 32 + m * 16 + lg * 4;
                f32x4 bb = *(const f32x4*)&bb1s[f0];
                #pragma unroll
                for (int nt = 0; nt < 4; ++nt) {
                    int j = nt * 16 + l15;
                    float q0 = lrelu(acc[m][nt][0] + bb[0]);
                    float q1 = lrelu(acc[m][nt][1] + bb[1]);
                    float q2 = lrelu(acc[m][nt][2] + bb[2]);
                    float q3 = lrelu(acc[m][nt][3] + bb[3]);
                    u32x2 pv; pv[0] = pack2(q0, q1); pv[1] = pack2(q2, q3);
                    *(u32x2*)(h1 + ((j * 512 + f0 * 2) ^ ((j & 7) << 4))) = pv;
                }
            }
        }
        __syncthreads();
        // ---- phase B: BUILD(ii+1) (global v loads issue early, hide under GEMM2)
        //              then GEMM2 + aggregate (waves 0-5) ----
        if (ii < 15) BUILD(ii + 1);
        if (wid < 6) {
            f32x4 acc2[4];
            #pragma unroll
            for (int nt = 0; nt < 4; ++nt) acc2[nt] = (f32x4){0.f, 0.f, 0.f, 0.f};
            #pragma unroll
            for (int ks = 0; ks < 8; ++ks) {
                #pragma unroll
                for (int nt = 0; nt < 4; ++nt) {
                    int j = nt * 16 + l15;
                    short8 bfr = *(const short8*)(h1 + ((j * 512 + (ks * 32 + lg * 8) * 2) ^ ((j & 7) << 4)));
                    acc2[nt] = __builtin_amdgcn_mfma_f32_16x16x32_bf16(a2[ks], bfr, acc2[nt], 0, 0, 0);
                }
            }
            const int f0 = wid * 16 + lg * 4;
            f32x4 bb = *(const f32x4*)&bb2s[f0];
            f32x4 s = (f32x4){0.f, 0.f, 0.f, 0.f};
            #pragma unroll
            for (int nt = 0; nt < 4; ++nt)
                #pragma unroll
                for (int r = 0; r < 4; ++r)
                    s[r] += lrelu(acc2[nt][r] + bb[r]);
            #pragma unroll
            for (int r = 0; r < 4; ++r) {
                float t = s[r];
                t += __shfl_xor(t, 1); t += __shfl_xor(t, 2);
                t += __shfl_xor(t, 4); t += __shfl_xor(t, 8);
                s[r] = t;
            }
            if (l15 == 0) *(f32x4*)&aggrow[ii * 96 + f0] = s;
        }
        __syncthreads();
    }
    #undef BUILD
}

// ---- node MLP ----
__global__ __launch_bounds__(256, 2)
void node_kernel(const float* __restrict__ x, const float* __restrict__ agg,
                 const short* __restrict__ Wn0T, const short* __restrict__ Wn1T,
                 const float* __restrict__ bn0, const float* __restrict__ bn1,
                 float* __restrict__ out)
{
    __shared__ short A2[64 * 168];
    __shared__ short H[64 * 264];
    const int tid = threadIdx.x;
    const int lane = tid & 63, wid = tid >> 6;
    const int l15 = lane & 15, lg = lane >> 4;
    const int r0 = blockIdx.x * 64;

    for (int t = tid; t < 64 * 160; t += 256) {
        int j = t / 160, c = t - j * 160;
        float vv = (c < 96) ? agg[(r0 + j) * 96 + c] : x[(r0 + j) * 64 + (c - 96)];
        A2[j * 168 + c] = f2bf(vv);
    }
    __syncthreads();

    {
        f32x4 acc[4][4];
        #pragma unroll
        for (int mt = 0; mt < 4; ++mt)
            #pragma unroll
            for (int nt = 0; nt < 4; ++nt) acc[mt][nt] = (f32x4){0.f, 0.f, 0.f, 0.f};
        const int n0 = wid * 64;
        #pragma unroll
        for (int ks = 0; ks < 5; ++ks) {
            const int k0 = ks * 32 + lg * 8;
            short8 a[4], bf[4];
            #pragma unroll
            for (int mt = 0; mt < 4; ++mt)
                a[mt] = *reinterpret_cast<const short8*>(&A2[(mt * 16 + l15) * 168 + k0]);
            #pragma unroll
            for (int nt = 0; nt < 4; ++nt)
                bf[nt] = *reinterpret_cast<const short8*>(&Wn0T[(n0 + nt * 16 + l15) * 160 + k0]);
            #pragma unroll
            for (int mt = 0; mt < 4; ++mt)
                #pragma unroll
                for (int nt = 0; nt < 4; ++nt)
                    acc[mt][nt] = __builtin_amdgcn_mfma_f32_16x16x32_bf16(a[mt], bf[nt], acc[mt][nt], 0, 0, 0);
        }
        #pragma unroll
        for (int nt = 0; nt < 4; ++nt) {
            const int col = n0 + nt * 16 + l15;
            const float bv = bn0[col];
            #pragma unroll
            for (int mt = 0; mt < 4; ++mt)
                #pragma unroll
                for (int r = 0; r < 4; ++r)
                    H[(mt * 16 + lg * 4 + r) * 264 + col] = f2bf(lrelu(acc[mt][nt][r] + bv));
        }
    }
    __syncthreads();

    {
        f32x4 acc[4];
        #pragma unroll
        for (int mt = 0; mt < 4; ++mt) acc[mt] = (f32x4){0.f, 0.f, 0.f, 0.f};
        #pragma unroll
        for (int ks = 0; ks < 8; ++ks) {
            const int k0 = ks * 32 + lg * 8;
            short8 bf = *reinterpret_cast<const short8*>(&Wn1T[(wid * 16 + l15) * 256 + k0]);
            #pragma unroll
            for (int mt = 0; mt < 4; ++mt) {
                short8 a = *reinterpret_cast<const short8*>(&H[(mt * 16 + l15) * 264 + k0]);
                acc[mt] = __builtin_amdgcn_mfma_f32_16x16x32_bf16(a, bf, acc[mt], 0, 0, 0);
            }
        }
        const int col = wid * 16 + l15;
        const float bv = bn1[col];
        #pragma unroll
        for (int mt = 0; mt < 4; ++mt)
            #pragma unroll
            for (int r = 0; r < 4; ++r)
                out[(r0 + mt * 16 + lg * 4 + r) * 64 + col] = acc[mt][r] + bv;
    }
}

extern "C" void kernel_launch(void* const* d_in, const int* in_sizes, int n_in,
                              void* d_out, int out_size, void* d_ws, size_t ws_size,
                              hipStream_t stream) {
    (void)in_sizes; (void)n_in; (void)out_size; (void)ws_size;
    const float* x    = (const float*)d_in[0];
    const float* feW0 = (const float*)d_in[1];
    const float* feb0 = (const float*)d_in[2];
    const float* feW1 = (const float*)d_in[3];
    const float* feb1 = (const float*)d_in[4];
    const float* feW2 = (const float*)d_in[5];
    const float* feb2 = (const float*)d_in[6];
    const float* fnW0 = (const float*)d_in[7];
    const float* fnb0 = (const float*)d_in[8];
    const float* fnW1 = (const float*)d_in[9];
    const float* fnb1 = (const float*)d_in[10];

    char* ws = (char*)d_ws;
    short* W1F   = (short*)(ws + 0);          // 131072
    short* W2F   = (short*)(ws + 131072);     // 65536
    short* W0uvF = (short*)(ws + 196608);     // 65536
    short* Wn0T  = (short*)(ws + 262144);     // 81920
    short* Wn1T  = (short*)(ws + 344064);     // 32768
    float* agg   = (float*)(ws + 376832);     // 3145728
    float* u     = (float*)(ws + 3522560);    // 8388608
    float* v     = (float*)(ws + 11911168);   // 8388608

    hipLaunchKernelGGL(prep_kernel, dim3(64), dim3(256), 0, stream,
                       feW0, feW1, feW2, fnW0, fnW1, W1F, W2F, W0uvF, Wn0T, Wn1T);
    hipLaunchKernelGGL(uv_kernel, dim3(128), dim3(256), 0, stream,
                       x, W0uvF, u, v);
    hipLaunchKernelGGL(edge_kernel, dim3(512), dim3(512), 0, stream,
                       x, feW0, feb0, feb1, feb2, W1F, W2F, u, v, agg);
    hipLaunchKernelGGL(node_kernel, dim3(128), dim3(256), 0, stream,
                       x, agg, Wn0T, Wn1T, fnb0, fnb1, (float*)d_out);
}

// Round 9
// 185.945 us; speedup vs baseline: 1.6373x; 1.0647x over previous
//
#include <hip/hip_runtime.h>

#define ALPHA 0.2f

typedef __attribute__((ext_vector_type(8))) short short8;
typedef __attribute__((ext_vector_type(4))) float f32x4;
typedef __attribute__((ext_vector_type(2))) unsigned int u32x2;
typedef __attribute__((ext_vector_type(4))) unsigned int u32x4;

__device__ __forceinline__ short f2bf(float f) {
    unsigned u = __builtin_bit_cast(unsigned, f);
    u += 0x7fffu + ((u >> 16) & 1u);   // RNE
    return (short)(u >> 16);
}
__device__ __forceinline__ unsigned pack2(float a, float b) {
    unsigned ua = __builtin_bit_cast(unsigned, a) + 0x8000u;
    unsigned ub = __builtin_bit_cast(unsigned, b) + 0x8000u;
    return (ua >> 16) | (ub & 0xffff0000u);
}
__device__ __forceinline__ float bf2f(short s) {
    return __builtin_bit_cast(float, ((unsigned)(unsigned short)s) << 16);
}
__device__ __forceinline__ float lrelu(float v) { return fmaxf(v, ALPHA * v); }

// ---- weight prep ----
__global__ void prep_kernel(const float* __restrict__ feW0, const float* __restrict__ feW1,
                            const float* __restrict__ feW2, const float* __restrict__ fnW0,
                            const float* __restrict__ fnW1,
                            short* __restrict__ W1F, short* __restrict__ W2F,
                            short* __restrict__ W0uvF,
                            short* __restrict__ Wn0T, short* __restrict__ Wn1T)
{
    const int tid = blockIdx.x * blockDim.x + threadIdx.x;
    const int T = gridDim.x * blockDim.x;
    // W1F fragment-linear: idx=((mt*8+ks)*64+lane)*8+e ; feat=mt*16+(lane&15); k=ks*32+(lane>>4)*8+e
    for (int t = tid; t < 65536; t += T) {
        int e = t & 7, lane = (t >> 3) & 63, ks = (t >> 9) & 7, mt = t >> 12;
        int feat = mt * 16 + (lane & 15), k = ks * 32 + (lane >> 4) * 8 + e;
        W1F[t] = f2bf(feW1[k * 256 + feat]);
    }
    // W2F: 128 feats (>=96 zero) x 256 k
    for (int t = tid; t < 32768; t += T) {
        int e = t & 7, lane = (t >> 3) & 63, ks = (t >> 9) & 7, mt = t >> 12;
        int feat = mt * 16 + (lane & 15), k = ks * 32 + (lane >> 4) * 8 + e;
        W2F[t] = f2bf(feat < 96 ? feW2[k * 96 + feat] : 0.f);
    }
    // W0uvF: 512 feats x 64 k; feat<256 -> W0a col, else W0b col
    for (int t = tid; t < 32768; t += T) {
        int e = t & 7, lane = (t >> 3) & 63, ks = (t >> 9) & 1, mt = t >> 10;
        int feat = mt * 16 + (lane & 15), k = ks * 32 + (lane >> 4) * 8 + e;
        float val = (feat < 256) ? feW0[k * 256 + feat] : feW0[(64 + k) * 256 + (feat - 256)];
        W0uvF[t] = f2bf(val);
    }
    for (int t = tid; t < 256 * 160; t += T) { int n = t / 160, k = t - n * 160; Wn0T[t] = f2bf(fnW0[k * 256 + n]); }
    for (int t = tid; t < 64 * 256; t += T) { int n = t >> 8, k = t & 255; Wn1T[t] = f2bf(fnW1[k * 64 + n]); }
}

// ---- u,v precompute ----
__global__ __launch_bounds__(256, 4)
void uv_kernel(const float* __restrict__ x, const short* __restrict__ W0uvF,
               float* __restrict__ u, float* __restrict__ v)
{
    __shared__ __align__(16) short xb[4096];
    const int tid = threadIdx.x;
    const int lane = tid & 63, wid = tid >> 6;
    const int l15 = lane & 15, lg = lane >> 4;
    const int r0 = blockIdx.x * 64;

    for (int t = tid; t < 4096; t += 256) {
        int row = t >> 6;
        int byte = (t * 2) ^ ((row & 7) << 4);
        *(short*)((char*)xb + byte) = f2bf(x[r0 * 64 + t]);
    }
    __syncthreads();

    #pragma unroll
    for (int pair = 0; pair < 4; ++pair) {
        const int mt0 = wid * 8 + pair * 2;
        f32x4 acc[2][4];
        #pragma unroll
        for (int m = 0; m < 2; ++m)
            #pragma unroll
            for (int nt = 0; nt < 4; ++nt) acc[m][nt] = (f32x4){0.f, 0.f, 0.f, 0.f};
        #pragma unroll
        for (int ks = 0; ks < 2; ++ks) {
            short8 a[2], bf[4];
            #pragma unroll
            for (int m = 0; m < 2; ++m)
                a[m] = *(const short8*)&W0uvF[(((mt0 + m) * 2 + ks) * 64 + lane) * 8];
            #pragma unroll
            for (int nt = 0; nt < 4; ++nt) {
                int row = nt * 16 + l15;
                int byte = (row * 128 + (ks * 32 + lg * 8) * 2) ^ ((row & 7) << 4);
                bf[nt] = *(const short8*)((char*)xb + byte);
            }
            #pragma unroll
            for (int m = 0; m < 2; ++m)
                #pragma unroll
                for (int nt = 0; nt < 4; ++nt)
                    acc[m][nt] = __builtin_amdgcn_mfma_f32_16x16x32_bf16(a[m], bf[nt], acc[m][nt], 0, 0, 0);
        }
        #pragma unroll
        for (int m = 0; m < 2; ++m) {
            int feat0 = (mt0 + m) * 16 + lg * 4;
            #pragma unroll
            for (int nt = 0; nt < 4; ++nt) {
                int R = r0 + nt * 16 + l15;
                float* dst = (feat0 < 256) ? &u[R * 256 + feat0] : &v[R * 256 + (feat0 - 256)];
                *(f32x4*)dst = acc[m][nt];
            }
        }
    }
}

// ---- edge MLP + aggregation: one block per (b, 16-i group); 512 threads, 8 waves.
// LDS = 55808 B (< 64 KB) to TEST the hypothesis that workgroups with LDS <= 64 KB
// can pack 2/CU (every >64KB config so far ran exclusively). j processed in halves
// of 32 per phase: h0/h1 are [32][256] bf16 (16 KB each). v read from global/L2
// in BUILD; ub is quad-swizzled f32 (conflict-free, R2-proven).
__global__ __launch_bounds__(512, 2)
void edge_kernel(const float* __restrict__ x, const float* __restrict__ feW0,
                 const float* __restrict__ b0v, const float* __restrict__ b1v,
                 const float* __restrict__ b2v,
                 const short* __restrict__ W1F, const short* __restrict__ W2F,
                 const float* __restrict__ u, const float* __restrict__ v,
                 float* __restrict__ agg)
{
    __shared__ __align__(16) char smem[55808];
    char* h0 = smem;                          // bf16 [32][256] swz    (16384)
    char* h1 = smem + 16384;                  // bf16 [32][256] swz    (16384)
    float* ub_f = (float*)(smem + 32768);     // f32 [16][64q] swz     (16384)
    float* wd_f = (float*)(smem + 49152);     // f32 [64q] swz         (1024)
    float* dist = (float*)(smem + 50176);     // f32 [16][64]          (4096)
    float* bb1s = (float*)(smem + 54272);     // f32 [256]             (1024)
    float* bb2s = (float*)(smem + 55296);     // f32 [96]              (512 pad)
    float* xs   = (float*)smem;               // alias h0+h1: f32 [64][68] (17408), prologue only

    const int tid = threadIdx.x;
    const int lane = tid & 63, wid = tid >> 6;
    const int l15 = lane & 15, lg = lane >> 4;
    const int j8 = tid >> 3, p8 = tid & 7;     // dist-phase roles
    const int jr = tid >> 4, c16 = tid & 15;   // BUILD roles: row 0..31, col-group
    const int b = blockIdx.x >> 2, i0 = (blockIdx.x & 3) * 16;
    const float* vbase = v + (size_t)b * 64 * 256;

    // ---- weight fragments -> registers (96 VGPR persistent, R2/R7-proven) ----
    short8 a1[2][8];   // W1 feats [wid*32, wid*32+32)
    #pragma unroll
    for (int m = 0; m < 2; ++m)
        #pragma unroll
        for (int ks = 0; ks < 8; ++ks)
            a1[m][ks] = *(const short8*)&W1F[(((wid * 2 + m) * 8 + ks) * 64 + lane) * 8];
    short8 a2[8];      // W2 feats [wid*16, wid*16+16), valid for wid<6
    #pragma unroll
    for (int ks = 0; ks < 8; ++ks)
        a2[ks] = *(const short8*)&W2F[((min(wid, 5) * 8 + ks) * 64 + lane) * 8];

    // ---- prologue staging ----
    {   // xs: x[b] f32 [64][68]
        const float* xb = x + b * 4096;
        *(f32x4*)&xs[j8 * 68 + p8 * 8]     = *(const f32x4*)&xb[j8 * 64 + p8 * 8];
        *(f32x4*)&xs[j8 * 68 + p8 * 8 + 4] = *(const f32x4*)&xb[j8 * 64 + p8 * 8 + 4];
    }
    {   // ub: f32 (u[b, i0+ii] + b0), quad-swizzled q^(q>>3) (conflict-free reads)
        int ii = tid >> 5, c0 = (tid & 31) * 8;
        f32x4 u0 = *(const f32x4*)&u[(b * 64 + i0 + ii) * 256 + c0];
        f32x4 u1 = *(const f32x4*)&u[(b * 64 + i0 + ii) * 256 + c0 + 4];
        u0 += *(const f32x4*)&b0v[c0];
        u1 += *(const f32x4*)&b0v[c0 + 4];
        int q = c0 >> 2;
        *(f32x4*)&ub_f[(q ^ (q >> 3)) * 4 + ii * 256] = u0;
        *(f32x4*)&ub_f[((q + 1) ^ ((q + 1) >> 3)) * 4 + ii * 256] = u1;
    }
    if (tid < 64) {
        f32x4 w0 = *(const f32x4*)&feW0[128 * 256 + tid * 4];
        *(f32x4*)&wd_f[(tid ^ (tid >> 3)) * 4] = w0;
    }
    if (tid < 256) bb1s[tid] = b1v[tid];
    else if (tid < 352) bb2s[tid - 256] = b2v[tid - 256];
    __syncthreads();

    // ---- dist[ii][j] (all 64 j, 16 i's) ----
    {
        f32x4 xj0 = *(const f32x4*)&xs[j8 * 68 + p8 * 8];
        f32x4 xj1 = *(const f32x4*)&xs[j8 * 68 + p8 * 8 + 4];
        #pragma unroll
        for (int ii = 0; ii < 16; ++ii) {
            const float* xi = &xs[(i0 + ii) * 68 + p8 * 8];
            f32x4 xi0 = *(const f32x4*)&xi[0];
            f32x4 xi1 = *(const f32x4*)&xi[4];
            float ss = 0.f;
            #pragma unroll
            for (int r = 0; r < 4; ++r) {
                float d0 = xj0[r] - xi0[r] + 1e-12f;
                float d1 = xj1[r] - xi1[r] + 1e-12f;
                ss += d0 * d0 + d1 * d1;
            }
            ss += __shfl_xor(ss, 1); ss += __shfl_xor(ss, 2); ss += __shfl_xor(ss, 4);
            if (p8 == 0) dist[ii * 64 + j8] = sqrtf(ss);
        }
    }
    __syncthreads();

    // BUILD step s_: h0 rows = j-half (s_&1), i-index (s_>>1).
    // thread: row jr (0..31), cols [c16*16, c16*16+16); v from global (L2).
    #define BUILD(s_) do { \
        int jj = ((s_) & 1) * 32 + jr; \
        float dj = dist[((s_) >> 1) * 64 + jj]; \
        const float* gv = vbase + jj * 256 + c16 * 16; \
        const float* ubrow = &ub_f[((s_) >> 1) * 256]; \
        _Pragma("unroll") \
        for (int k = 0; k < 2; ++k) { \
            f32x4 va = *(const f32x4*)&gv[k * 8]; \
            f32x4 vb4 = *(const f32x4*)&gv[k * 8 + 4]; \
            int q = c16 * 4 + k * 2; \
            f32x4 uu0 = *(const f32x4*)&ubrow[(q ^ (q >> 3)) * 4]; \
            f32x4 uu1 = *(const f32x4*)&ubrow[((q + 1) ^ ((q + 1) >> 3)) * 4]; \
            f32x4 ww0 = *(const f32x4*)&wd_f[(q ^ (q >> 3)) * 4]; \
            f32x4 ww1 = *(const f32x4*)&wd_f[((q + 1) ^ ((q + 1) >> 3)) * 4]; \
            float t0 = lrelu(uu0[0] + va[0] + dj * ww0[0]); \
            float t1 = lrelu(uu0[1] + va[1] + dj * ww0[1]); \
            float t2 = lrelu(uu0[2] + va[2] + dj * ww0[2]); \
            float t3 = lrelu(uu0[3] + va[3] + dj * ww0[3]); \
            float t4 = lrelu(uu1[0] + vb4[0] + dj * ww1[0]); \
            float t5 = lrelu(uu1[1] + vb4[1] + dj * ww1[1]); \
            float t6 = lrelu(uu1[2] + vb4[2] + dj * ww1[2]); \
            float t7 = lrelu(uu1[3] + vb4[3] + dj * ww1[3]); \
            u32x4 pk; \
            pk[0] = pack2(t0, t1); pk[1] = pack2(t2, t3); \
            pk[2] = pack2(t4, t5); pk[3] = pack2(t6, t7); \
            *(u32x4*)(h0 + ((jr * 512 + (c16 * 16 + k * 8) * 2) ^ ((jr & 7) << 4))) = pk; \
        } \
    } while (0)

    BUILD(0);
    __syncthreads();

    float* aggrow = agg + (b * 64 + i0) * 96;
    f32x4 sacc = (f32x4){0.f, 0.f, 0.f, 0.f};

    for (int s = 0; s < 32; ++s) {
        // ---- phase A: GEMM1  h1 = lrelu(W1 @ h0 + b1), N=32 (this j-half) ----
        {
            f32x4 acc[2][2];
            acc[0][0] = (f32x4){0.f,0.f,0.f,0.f}; acc[0][1] = (f32x4){0.f,0.f,0.f,0.f};
            acc[1][0] = (f32x4){0.f,0.f,0.f,0.f}; acc[1][1] = (f32x4){0.f,0.f,0.f,0.f};
            #pragma unroll
            for (int ks = 0; ks < 8; ++ks) {
                short8 bfr[2];
                #pragma unroll
                for (int nt = 0; nt < 2; ++nt) {
                    int j = nt * 16 + l15;
                    bfr[nt] = *(const short8*)(h0 + ((j * 512 + (ks * 32 + lg * 8) * 2) ^ ((j & 7) << 4)));
                }
                #pragma unroll
                for (int m = 0; m < 2; ++m)
                    #pragma unroll
                    for (int nt = 0; nt < 2; ++nt)
                        acc[m][nt] = __builtin_amdgcn_mfma_f32_16x16x32_bf16(a1[m][ks], bfr[nt], acc[m][nt], 0, 0, 0);
            }
            #pragma unroll
            for (int m = 0; m < 2; ++m) {
                int f0 = wid * 32 + m * 16 + lg * 4;
                f32x4 bb = *(const f32x4*)&bb1s[f0];
                #pragma unroll
                for (int nt = 0; nt < 2; ++nt) {
                    int j = nt * 16 + l15;
                    float q0 = lrelu(acc[m][nt][0] + bb[0]);
                    float q1 = lrelu(acc[m][nt][1] + bb[1]);
                    float q2 = lrelu(acc[m][nt][2] + bb[2]);
                    float q3 = lrelu(acc[m][nt][3] + bb[3]);
                    u32x2 pv; pv[0] = pack2(q0, q1); pv[1] = pack2(q2, q3);
                    *(u32x2*)(h1 + ((j * 512 + f0 * 2) ^ ((j & 7) << 4))) = pv;
                }
            }
        }
        __syncthreads();
        // ---- phase B: BUILD(s+1), then GEMM2 half + accumulate ----
        if (s < 31) BUILD(s + 1);
        if (wid < 6) {
            f32x4 acc2[2];
            acc2[0] = (f32x4){0.f,0.f,0.f,0.f}; acc2[1] = (f32x4){0.f,0.f,0.f,0.f};
            #pragma unroll
            for (int ks = 0; ks < 8; ++ks) {
                #pragma unroll
                for (int nt = 0; nt < 2; ++nt) {
                    int j = nt * 16 + l15;
                    short8 bfr = *(const short8*)(h1 + ((j * 512 + (ks * 32 + lg * 8) * 2) ^ ((j & 7) << 4)));
                    acc2[nt] = __builtin_amdgcn_mfma_f32_16x16x32_bf16(a2[ks], bfr, acc2[nt], 0, 0, 0);
                }
            }
            const int f0 = wid * 16 + lg * 4;
            f32x4 bb = *(const f32x4*)&bb2s[f0];
            #pragma unroll
            for (int r = 0; r < 4; ++r)
                sacc[r] += lrelu(acc2[0][r] + bb[r]) + lrelu(acc2[1][r] + bb[r]);
            if (s & 1) {   // second half done: reduce over j-lanes, write agg row
                #pragma unroll
                for (int r = 0; r < 4; ++r) {
                    float t = sacc[r];
                    t += __shfl_xor(t, 1); t += __shfl_xor(t, 2);
                    t += __shfl_xor(t, 4); t += __shfl_xor(t, 8);
                    sacc[r] = t;
                }
                if (l15 == 0) *(f32x4*)&aggrow[(s >> 1) * 96 + f0] = sacc;
                sacc = (f32x4){0.f, 0.f, 0.f, 0.f};
            }
        }
        __syncthreads();
    }
    #undef BUILD
}

// ---- node MLP ----
__global__ __launch_bounds__(256, 2)
void node_kernel(const float* __restrict__ x, const float* __restrict__ agg,
                 const short* __restrict__ Wn0T, const short* __restrict__ Wn1T,
                 const float* __restrict__ bn0, const float* __restrict__ bn1,
                 float* __restrict__ out)
{
    __shared__ short A2[64 * 168];
    __shared__ short H[64 * 264];
    const int tid = threadIdx.x;
    const int lane = tid & 63, wid = tid >> 6;
    const int l15 = lane & 15, lg = lane >> 4;
    const int r0 = blockIdx.x * 64;

    for (int t = tid; t < 64 * 160; t += 256) {
        int j = t / 160, c = t - j * 160;
        float vv = (c < 96) ? agg[(r0 + j) * 96 + c] : x[(r0 + j) * 64 + (c - 96)];
        A2[j * 168 + c] = f2bf(vv);
    }
    __syncthreads();

    {
        f32x4 acc[4][4];
        #pragma unroll
        for (int mt = 0; mt < 4; ++mt)
            #pragma unroll
            for (int nt = 0; nt < 4; ++nt) acc[mt][nt] = (f32x4){0.f, 0.f, 0.f, 0.f};
        const int n0 = wid * 64;
        #pragma unroll
        for (int ks = 0; ks < 5; ++ks) {
            const int k0 = ks * 32 + lg * 8;
            short8 a[4], bf[4];
            #pragma unroll
            for (int mt = 0; mt < 4; ++mt)
                a[mt] = *reinterpret_cast<const short8*>(&A2[(mt * 16 + l15) * 168 + k0]);
            #pragma unroll
            for (int nt = 0; nt < 4; ++nt)
                bf[nt] = *reinterpret_cast<const short8*>(&Wn0T[(n0 + nt * 16 + l15) * 160 + k0]);
            #pragma unroll
            for (int mt = 0; mt < 4; ++mt)
                #pragma unroll
                for (int nt = 0; nt < 4; ++nt)
                    acc[mt][nt] = __builtin_amdgcn_mfma_f32_16x16x32_bf16(a[mt], bf[nt], acc[mt][nt], 0, 0, 0);
        }
        #pragma unroll
        for (int nt = 0; nt < 4; ++nt) {
            const int col = n0 + nt * 16 + l15;
            const float bv = bn0[col];
            #pragma unroll
            for (int mt = 0; mt < 4; ++mt)
                #pragma unroll
                for (int r = 0; r < 4; ++r)
                    H[(mt * 16 + lg * 4 + r) * 264 + col] = f2bf(lrelu(acc[mt][nt][r] + bv));
        }
    }
    __syncthreads();

    {
        f32x4 acc[4];
        #pragma unroll
        for (int mt = 0; mt < 4; ++mt) acc[mt] = (f32x4){0.f, 0.f, 0.f, 0.f};
        #pragma unroll
        for (int ks = 0; ks < 8; ++ks) {
            const int k0 = ks * 32 + lg * 8;
            short8 bf = *reinterpret_cast<const short8*>(&Wn1T[(wid * 16 + l15) * 256 + k0]);
            #pragma unroll
            for (int mt = 0; mt < 4; ++mt) {
                short8 a = *reinterpret_cast<const short8*>(&H[(mt * 16 + l15) * 264 + k0]);
                acc[mt] = __builtin_amdgcn_mfma_f32_16x16x32_bf16(a, bf, acc[mt], 0, 0, 0);
            }
        }
        const int col = wid * 16 + l15;
        const float bv = bn1[col];
        #pragma unroll
        for (int mt = 0; mt < 4; ++mt)
            #pragma unroll
            for (int r = 0; r < 4; ++r)
                out[(r0 + mt * 16 + lg * 4 + r) * 64 + col] = acc[mt][r] + bv;
    }
}

extern "C" void kernel_launch(void* const* d_in, const int* in_sizes, int n_in,
                              void* d_out, int out_size, void* d_ws, size_t ws_size,
                              hipStream_t stream) {
    (void)in_sizes; (void)n_in; (void)out_size; (void)ws_size;
    const float* x    = (const float*)d_in[0];
    const float* feW0 = (const float*)d_in[1];
    const float* feb0 = (const float*)d_in[2];
    const float* feW1 = (const float*)d_in[3];
    const float* feb1 = (const float*)d_in[4];
    const float* feW2 = (const float*)d_in[5];
    const float* feb2 = (const float*)d_in[6];
    const float* fnW0 = (const float*)d_in[7];
    const float* fnb0 = (const float*)d_in[8];
    const float* fnW1 = (const float*)d_in[9];
    const float* fnb1 = (const float*)d_in[10];

    char* ws = (char*)d_ws;
    short* W1F   = (short*)(ws + 0);          // 131072
    short* W2F   = (short*)(ws + 131072);     // 65536
    short* W0uvF = (short*)(ws + 196608);     // 65536
    short* Wn0T  = (short*)(ws + 262144);     // 81920
    short* Wn1T  = (short*)(ws + 344064);     // 32768
    float* agg   = (float*)(ws + 376832);     // 3145728
    float* u     = (float*)(ws + 3522560);    // 8388608
    float* v     = (float*)(ws + 11911168);   // 8388608

    hipLaunchKernelGGL(prep_kernel, dim3(64), dim3(256), 0, stream,
                       feW0, feW1, feW2, fnW0, fnW1, W1F, W2F, W0uvF, Wn0T, Wn1T);
    hipLaunchKernelGGL(uv_kernel, dim3(128), dim3(256), 0, stream,
                       x, W0uvF, u, v);
    hipLaunchKernelGGL(edge_kernel, dim3(512), dim3(512), 0, stream,
                       x, feW0, feb0, feb1, feb2, W1F, W2F, u, v, agg);
    hipLaunchKernelGGL(node_kernel, dim3(128), dim3(256), 0, stream,
                       x, agg, Wn0T, Wn1T, fnb0, fnb1, (float*)d_out);
}

// Round 10
// 165.032 us; speedup vs baseline: 1.8448x; 1.1267x over previous
//
#include <hip/hip_runtime.h>

#define ALPHA 0.2f

typedef __attribute__((ext_vector_type(8))) short short8;
typedef __attribute__((ext_vector_type(4))) float f32x4;
typedef __attribute__((ext_vector_type(2))) unsigned int u32x2;
typedef __attribute__((ext_vector_type(4))) unsigned int u32x4;

__device__ __forceinline__ short f2bf(float f) {
    unsigned u = __builtin_bit_cast(unsigned, f);
    u += 0x7fffu + ((u >> 16) & 1u);   // RNE
    return (short)(u >> 16);
}
__device__ __forceinline__ unsigned pack2(float a, float b) {
    unsigned ua = __builtin_bit_cast(unsigned, a) + 0x8000u;
    unsigned ub = __builtin_bit_cast(unsigned, b) + 0x8000u;
    return (ua >> 16) | (ub & 0xffff0000u);
}
__device__ __forceinline__ float lrelu(float v) { return fmaxf(v, ALPHA * v); }

// ---- weight prep ----
__global__ void prep_kernel(const float* __restrict__ feW0, const float* __restrict__ feW1,
                            const float* __restrict__ feW2, const float* __restrict__ fnW0,
                            const float* __restrict__ fnW1,
                            short* __restrict__ W1F, short* __restrict__ W2F,
                            short* __restrict__ W0uvF,
                            short* __restrict__ Wn0T, short* __restrict__ Wn1T)
{
    const int tid = blockIdx.x * blockDim.x + threadIdx.x;
    const int T = gridDim.x * blockDim.x;
    // W1F fragment-linear: idx=((mt*8+ks)*64+lane)*8+e ; feat=mt*16+(lane&15); k=ks*32+(lane>>4)*8+e
    for (int t = tid; t < 65536; t += T) {
        int e = t & 7, lane = (t >> 3) & 63, ks = (t >> 9) & 7, mt = t >> 12;
        int feat = mt * 16 + (lane & 15), k = ks * 32 + (lane >> 4) * 8 + e;
        W1F[t] = f2bf(feW1[k * 256 + feat]);
    }
    // W2F: 128 feats (>=96 zero) x 256 k
    for (int t = tid; t < 32768; t += T) {
        int e = t & 7, lane = (t >> 3) & 63, ks = (t >> 9) & 7, mt = t >> 12;
        int feat = mt * 16 + (lane & 15), k = ks * 32 + (lane >> 4) * 8 + e;
        W2F[t] = f2bf(feat < 96 ? feW2[k * 96 + feat] : 0.f);
    }
    // W0uvF: 512 feats x 64 k; feat<256 -> W0a col, else W0b col
    for (int t = tid; t < 32768; t += T) {
        int e = t & 7, lane = (t >> 3) & 63, ks = (t >> 9) & 1, mt = t >> 10;
        int feat = mt * 16 + (lane & 15), k = ks * 32 + (lane >> 4) * 8 + e;
        float val = (feat < 256) ? feW0[k * 256 + feat] : feW0[(64 + k) * 256 + (feat - 256)];
        W0uvF[t] = f2bf(val);
    }
    for (int t = tid; t < 256 * 160; t += T) { int n = t / 160, k = t - n * 160; Wn0T[t] = f2bf(fnW0[k * 256 + n]); }
    for (int t = tid; t < 64 * 256; t += T) { int n = t >> 8, k = t & 255; Wn1T[t] = f2bf(fnW1[k * 64 + n]); }
}

// ---- u,v precompute ----
__global__ __launch_bounds__(256, 4)
void uv_kernel(const float* __restrict__ x, const short* __restrict__ W0uvF,
               float* __restrict__ u, float* __restrict__ v)
{
    __shared__ __align__(16) short xb[4096];
    const int tid = threadIdx.x;
    const int lane = tid & 63, wid = tid >> 6;
    const int l15 = lane & 15, lg = lane >> 4;
    const int r0 = blockIdx.x * 64;

    for (int t = tid; t < 4096; t += 256) {
        int row = t >> 6;
        int byte = (t * 2) ^ ((row & 7) << 4);
        *(short*)((char*)xb + byte) = f2bf(x[r0 * 64 + t]);
    }
    __syncthreads();

    #pragma unroll
    for (int pair = 0; pair < 4; ++pair) {
        const int mt0 = wid * 8 + pair * 2;
        f32x4 acc[2][4];
        #pragma unroll
        for (int m = 0; m < 2; ++m)
            #pragma unroll
            for (int nt = 0; nt < 4; ++nt) acc[m][nt] = (f32x4){0.f, 0.f, 0.f, 0.f};
        #pragma unroll
        for (int ks = 0; ks < 2; ++ks) {
            short8 a[2], bf[4];
            #pragma unroll
            for (int m = 0; m < 2; ++m)
                a[m] = *(const short8*)&W0uvF[(((mt0 + m) * 2 + ks) * 64 + lane) * 8];
            #pragma unroll
            for (int nt = 0; nt < 4; ++nt) {
                int row = nt * 16 + l15;
                int byte = (row * 128 + (ks * 32 + lg * 8) * 2) ^ ((row & 7) << 4);
                bf[nt] = *(const short8*)((char*)xb + byte);
            }
            #pragma unroll
            for (int m = 0; m < 2; ++m)
                #pragma unroll
                for (int nt = 0; nt < 4; ++nt)
                    acc[m][nt] = __builtin_amdgcn_mfma_f32_16x16x32_bf16(a[m], bf[nt], acc[m][nt], 0, 0, 0);
        }
        #pragma unroll
        for (int m = 0; m < 2; ++m) {
            int feat0 = (mt0 + m) * 16 + lg * 4;
            #pragma unroll
            for (int nt = 0; nt < 4; ++nt) {
                int R = r0 + nt * 16 + l15;
                float* dst = (feat0 < 256) ? &u[R * 256 + feat0] : &v[R * 256 + (feat0 - 256)];
                *(f32x4*)dst = acc[m][nt];
            }
        }
    }
}

// ---- edge MLP + aggregation: one block per (b, 16-i group); 512 threads, 8 waves.
// Single-barrier software pipeline (17 phases): phase s runs
//   GEMM1(i=s)   : h0[s&1] -> h1[s&1]          (all 8 waves, 64 MFMA each)
//   BUILD(i=s+1) : v(global/L2)+ub+wd -> h0[(s+1)&1]  (all waves, VALU)
//   GEMM2(i=s-1) : h1[(s-1)&1] -> agg row      (waves 0-5; a2 loaded from L2)
// Double-buffered h0/h1 make these hazard-free within a phase; 1 barrier/phase.
// Occupancy is pinned at 1 block/CU on this machine regardless of LDS (R2/R7/R8
// evidence), so we spend LDS freely (154 KB) and loosen the VGPR cap (512,1).
__global__ __launch_bounds__(512, 1)
void edge_kernel(const float* __restrict__ x, const float* __restrict__ feW0,
                 const float* __restrict__ b0v, const float* __restrict__ b1v,
                 const float* __restrict__ b2v,
                 const short* __restrict__ W1F, const short* __restrict__ W2F,
                 const float* __restrict__ u, const float* __restrict__ v,
                 float* __restrict__ agg)
{
    __shared__ __align__(16) char smem[154112];
    // h0[0]:0  h0[1]:32768  h1[0]:65536  h1[1]:98304  (bf16 [64][256] XOR-swz each)
    float* ub_f = (float*)(smem + 131072);   // f32 [16][64q] quad-swz (16384)
    float* wd_f = (float*)(smem + 147456);   // f32 [64q] quad-swz     (1024)
    float* dist = (float*)(smem + 148480);   // f32 [16][64]           (4096)
    float* bb1s = (float*)(smem + 152576);   // f32 [256]              (1024)
    float* bb2s = (float*)(smem + 153600);   // f32 [96] (+pad)        (512)
    float* xs   = (float*)(smem + 65536);    // alias h1[0]: f32 [64][68], prologue only

    const int tid = threadIdx.x;
    const int lane = tid & 63, wid = tid >> 6;
    const int l15 = lane & 15, lg = lane >> 4;
    const int j8 = tid >> 3, p8 = tid & 7;
    const int b = blockIdx.x >> 2, i0 = (blockIdx.x & 3) * 16;
    const float* vbase = v + (size_t)b * 16384;

    // ---- persistent W1 fragments (64 VGPR) ----
    short8 a1[2][8];   // feats [wid*32, wid*32+32)
    #pragma unroll
    for (int m = 0; m < 2; ++m)
        #pragma unroll
        for (int ks = 0; ks < 8; ++ks)
            a1[m][ks] = *(const short8*)&W1F[(((wid * 2 + m) * 8 + ks) * 64 + lane) * 8];

    // ---- prologue staging ----
    {   // xs: x[b] f32 [64][68]
        const float* xb = x + b * 4096;
        *(f32x4*)&xs[j8 * 68 + p8 * 8]     = *(const f32x4*)&xb[j8 * 64 + p8 * 8];
        *(f32x4*)&xs[j8 * 68 + p8 * 8 + 4] = *(const f32x4*)&xb[j8 * 64 + p8 * 8 + 4];
    }
    {   // ub: f32 (u[b, i0+ii] + b0), quad-swizzled q^(q>>3)
        int ii = tid >> 5, c0 = (tid & 31) * 8;
        f32x4 u0 = *(const f32x4*)&u[(b * 64 + i0 + ii) * 256 + c0];
        f32x4 u1 = *(const f32x4*)&u[(b * 64 + i0 + ii) * 256 + c0 + 4];
        u0 += *(const f32x4*)&b0v[c0];
        u1 += *(const f32x4*)&b0v[c0 + 4];
        int q = c0 >> 2;
        *(f32x4*)&ub_f[(q ^ (q >> 3)) * 4 + ii * 256] = u0;
        *(f32x4*)&ub_f[((q + 1) ^ ((q + 1) >> 3)) * 4 + ii * 256] = u1;
    }
    if (tid < 64) {
        f32x4 w0 = *(const f32x4*)&feW0[128 * 256 + tid * 4];
        *(f32x4*)&wd_f[(tid ^ (tid >> 3)) * 4] = w0;
    }
    if (tid < 256) bb1s[tid] = b1v[tid];
    else if (tid < 352) bb2s[tid - 256] = b2v[tid - 256];
    __syncthreads();

    // ---- dist[ii][j] ----
    {
        f32x4 xj0 = *(const f32x4*)&xs[j8 * 68 + p8 * 8];
        f32x4 xj1 = *(const f32x4*)&xs[j8 * 68 + p8 * 8 + 4];
        #pragma unroll
        for (int ii = 0; ii < 16; ++ii) {
            const float* xi = &xs[(i0 + ii) * 68 + p8 * 8];
            f32x4 xi0 = *(const f32x4*)&xi[0];
            f32x4 xi1 = *(const f32x4*)&xi[4];
            float ss = 0.f;
            #pragma unroll
            for (int r = 0; r < 4; ++r) {
                float d0 = xj0[r] - xi0[r] + 1e-12f;
                float d1 = xj1[r] - xi1[r] + 1e-12f;
                ss += d0 * d0 + d1 * d1;
            }
            ss += __shfl_xor(ss, 1); ss += __shfl_xor(ss, 2); ss += __shfl_xor(ss, 4);
            if (p8 == 0) dist[ii * 64 + j8] = sqrtf(ss);
        }
    }
    __syncthreads();

    // BUILD node t_: thread handles row j8, cols [e*64 + p8*8, +8) per e (coalesced
    // v reads: 8 lanes x 32B contiguous per row). ub/wd reads broadcast across j8.
    #define BUILD(t_, dst_) do { \
        float dj = dist[(t_) * 64 + j8]; \
        const float* gv = vbase + j8 * 256; \
        const float* ubrow = &ub_f[(t_) * 256]; \
        _Pragma("unroll") \
        for (int e = 0; e < 4; ++e) { \
            int c0 = e * 64 + p8 * 8; \
            f32x4 va = *(const f32x4*)&gv[c0]; \
            f32x4 vb4 = *(const f32x4*)&gv[c0 + 4]; \
            int q0 = c0 >> 2; \
            int s0 = (q0 ^ (q0 >> 3)) * 4, s1 = ((q0 + 1) ^ ((q0 + 1) >> 3)) * 4; \
            f32x4 uu0 = *(const f32x4*)&ubrow[s0]; \
            f32x4 uu1 = *(const f32x4*)&ubrow[s1]; \
            f32x4 ww0 = *(const f32x4*)&wd_f[s0]; \
            f32x4 ww1 = *(const f32x4*)&wd_f[s1]; \
            float t0 = lrelu(uu0[0] + va[0] + dj * ww0[0]); \
            float t1 = lrelu(uu0[1] + va[1] + dj * ww0[1]); \
            float t2 = lrelu(uu0[2] + va[2] + dj * ww0[2]); \
            float t3 = lrelu(uu0[3] + va[3] + dj * ww0[3]); \
            float t4 = lrelu(uu1[0] + vb4[0] + dj * ww1[0]); \
            float t5 = lrelu(uu1[1] + vb4[1] + dj * ww1[1]); \
            float t6 = lrelu(uu1[2] + vb4[2] + dj * ww1[2]); \
            float t7 = lrelu(uu1[3] + vb4[3] + dj * ww1[3]); \
            u32x4 pk; \
            pk[0] = pack2(t0, t1); pk[1] = pack2(t2, t3); \
            pk[2] = pack2(t4, t5); pk[3] = pack2(t6, t7); \
            *(u32x4*)((dst_) + ((j8 * 512 + c0 * 2) ^ ((j8 & 7) << 4))) = pk; \
        } \
    } while (0)

    BUILD(0, smem);
    __syncthreads();

    float* aggrow = agg + (b * 64 + i0) * 96;

    for (int s = 0; s <= 16; ++s) {
        char* h0c = smem + ((s & 1) << 15);
        char* h0n = smem + (((s + 1) & 1) << 15);
        char* h1c = smem + 65536 + ((s & 1) << 15);
        char* h1p = smem + 65536 + (((s + 1) & 1) << 15);   // (s-1)&1 == (s+1)&1

        // ---- GEMM1(i=s): h1c = lrelu(W1 @ h0c + b1) ----
        if (s < 16) {
            f32x4 acc[2][4];
            #pragma unroll
            for (int m = 0; m < 2; ++m)
                #pragma unroll
                for (int nt = 0; nt < 4; ++nt) acc[m][nt] = (f32x4){0.f, 0.f, 0.f, 0.f};
            #pragma unroll
            for (int ks = 0; ks < 8; ++ks) {
                short8 bfr[4];
                #pragma unroll
                for (int nt = 0; nt < 4; ++nt) {
                    int j = nt * 16 + l15;
                    bfr[nt] = *(const short8*)(h0c + ((j * 512 + (ks * 32 + lg * 8) * 2) ^ ((j & 7) << 4)));
                }
                #pragma unroll
                for (int m = 0; m < 2; ++m)
                    #pragma unroll
                    for (int nt = 0; nt < 4; ++nt)
                        acc[m][nt] = __builtin_amdgcn_mfma_f32_16x16x32_bf16(a1[m][ks], bfr[nt], acc[m][nt], 0, 0, 0);
            }
            #pragma unroll
            for (int m = 0; m < 2; ++m) {
                int f0 = wid * 32 + m * 16 + lg * 4;
                f32x4 bb = *(const f32x4*)&bb1s[f0];
                #pragma unroll
                for (int nt = 0; nt < 4; ++nt) {
                    int j = nt * 16 + l15;
                    float q0 = lrelu(acc[m][nt][0] + bb[0]);
                    float q1 = lrelu(acc[m][nt][1] + bb[1]);
                    float q2 = lrelu(acc[m][nt][2] + bb[2]);
                    float q3 = lrelu(acc[m][nt][3] + bb[3]);
                    u32x2 pv; pv[0] = pack2(q0, q1); pv[1] = pack2(q2, q3);
                    *(u32x2*)(h1c + ((j * 512 + f0 * 2) ^ ((j & 7) << 4))) = pv;
                }
            }
        }

        // ---- BUILD(i=s+1) into h0n ----
        if (s + 1 < 16) BUILD(s + 1, h0n);

        // ---- GEMM2(i=s-1): agg row from h1p (waves 0-5; a2 from L2) ----
        if (s >= 1 && wid < 6) {
            short8 a2f[8];
            #pragma unroll
            for (int ks = 0; ks < 8; ++ks)
                a2f[ks] = *(const short8*)&W2F[((wid * 8 + ks) * 64 + lane) * 8];
            f32x4 acc2[4];
            #pragma unroll
            for (int nt = 0; nt < 4; ++nt) acc2[nt] = (f32x4){0.f, 0.f, 0.f, 0.f};
            #pragma unroll
            for (int ks = 0; ks < 8; ++ks) {
                #pragma unroll
                for (int nt = 0; nt < 4; ++nt) {
                    int j = nt * 16 + l15;
                    short8 bfr = *(const short8*)(h1p + ((j * 512 + (ks * 32 + lg * 8) * 2) ^ ((j & 7) << 4)));
                    acc2[nt] = __builtin_amdgcn_mfma_f32_16x16x32_bf16(a2f[ks], bfr, acc2[nt], 0, 0, 0);
                }
            }
            const int f0 = wid * 16 + lg * 4;
            f32x4 bb = *(const f32x4*)&bb2s[f0];
            f32x4 ssum = (f32x4){0.f, 0.f, 0.f, 0.f};
            #pragma unroll
            for (int nt = 0; nt < 4; ++nt)
                #pragma unroll
                for (int r = 0; r < 4; ++r)
                    ssum[r] += lrelu(acc2[nt][r] + bb[r]);
            #pragma unroll
            for (int r = 0; r < 4; ++r) {
                float t = ssum[r];
                t += __shfl_xor(t, 1); t += __shfl_xor(t, 2);
                t += __shfl_xor(t, 4); t += __shfl_xor(t, 8);
                ssum[r] = t;
            }
            if (l15 == 0) *(f32x4*)&aggrow[(s - 1) * 96 + f0] = ssum;
        }

        __syncthreads();
    }
    #undef BUILD
}

// ---- node MLP ----
__global__ __launch_bounds__(256, 2)
void node_kernel(const float* __restrict__ x, const float* __restrict__ agg,
                 const short* __restrict__ Wn0T, const short* __restrict__ Wn1T,
                 const float* __restrict__ bn0, const float* __restrict__ bn1,
                 float* __restrict__ out)
{
    __shared__ short A2[64 * 168];
    __shared__ short H[64 * 264];
    const int tid = threadIdx.x;
    const int lane = tid & 63, wid = tid >> 6;
    const int l15 = lane & 15, lg = lane >> 4;
    const int r0 = blockIdx.x * 64;

    for (int t = tid; t < 64 * 160; t += 256) {
        int j = t / 160, c = t - j * 160;
        float vv = (c < 96) ? agg[(r0 + j) * 96 + c] : x[(r0 + j) * 64 + (c - 96)];
        A2[j * 168 + c] = f2bf(vv);
    }
    __syncthreads();

    {
        f32x4 acc[4][4];
        #pragma unroll
        for (int mt = 0; mt < 4; ++mt)
            #pragma unroll
            for (int nt = 0; nt < 4; ++nt) acc[mt][nt] = (f32x4){0.f, 0.f, 0.f, 0.f};
        const int n0 = wid * 64;
        #pragma unroll
        for (int ks = 0; ks < 5; ++ks) {
            const int k0 = ks * 32 + lg * 8;
            short8 a[4], bf[4];
            #pragma unroll
            for (int mt = 0; mt < 4; ++mt)
                a[mt] = *reinterpret_cast<const short8*>(&A2[(mt * 16 + l15) * 168 + k0]);
            #pragma unroll
            for (int nt = 0; nt < 4; ++nt)
                bf[nt] = *reinterpret_cast<const short8*>(&Wn0T[(n0 + nt * 16 + l15) * 160 + k0]);
            #pragma unroll
            for (int mt = 0; mt < 4; ++mt)
                #pragma unroll
                for (int nt = 0; nt < 4; ++nt)
                    acc[mt][nt] = __builtin_amdgcn_mfma_f32_16x16x32_bf16(a[mt], bf[nt], acc[mt][nt], 0, 0, 0);
        }
        #pragma unroll
        for (int nt = 0; nt < 4; ++nt) {
            const int col = n0 + nt * 16 + l15;
            const float bv = bn0[col];
            #pragma unroll
            for (int mt = 0; mt < 4; ++mt)
                #pragma unroll
                for (int r = 0; r < 4; ++r)
                    H[(mt * 16 + lg * 4 + r) * 264 + col] = f2bf(lrelu(acc[mt][nt][r] + bv));
        }
    }
    __syncthreads();

    {
        f32x4 acc[4];
        #pragma unroll
        for (int mt = 0; mt < 4; ++mt) acc[mt] = (f32x4){0.f, 0.f, 0.f, 0.f};
        #pragma unroll
        for (int ks = 0; ks < 8; ++ks) {
            const int k0 = ks * 32 + lg * 8;
            short8 bf = *reinterpret_cast<const short8*>(&Wn1T[(wid * 16 + l15) * 256 + k0]);
            #pragma unroll
            for (int mt = 0; mt < 4; ++mt) {
                short8 a = *reinterpret_cast<const short8*>(&H[(mt * 16 + l15) * 264 + k0]);
                acc[mt] = __builtin_amdgcn_mfma_f32_16x16x32_bf16(a, bf, acc[mt], 0, 0, 0);
            }
        }
        const int col = wid * 16 + l15;
        const float bv = bn1[col];
        #pragma unroll
        for (int mt = 0; mt < 4; ++mt)
            #pragma unroll
            for (int r = 0; r < 4; ++r)
                out[(r0 + mt * 16 + lg * 4 + r) * 64 + col] = acc[mt][r] + bv;
    }
}

extern "C" void kernel_launch(void* const* d_in, const int* in_sizes, int n_in,
                              void* d_out, int out_size, void* d_ws, size_t ws_size,
                              hipStream_t stream) {
    (void)in_sizes; (void)n_in; (void)out_size; (void)ws_size;
    const float* x    = (const float*)d_in[0];
    const float* feW0 = (const float*)d_in[1];
    const float* feb0 = (const float*)d_in[2];
    const float* feW1 = (const float*)d_in[3];
    const float* feb1 = (const float*)d_in[4];
    const float* feW2 = (const float*)d_in[5];
    const float* feb2 = (const float*)d_in[6];
    const float* fnW0 = (const float*)d_in[7];
    const float* fnb0 = (const float*)d_in[8];
    const float* fnW1 = (const float*)d_in[9];
    const float* fnb1 = (const float*)d_in[10];

    char* ws = (char*)d_ws;
    short* W1F   = (short*)(ws + 0);          // 131072
    short* W2F   = (short*)(ws + 131072);     // 65536
    short* W0uvF = (short*)(ws + 196608);     // 65536
    short* Wn0T  = (short*)(ws + 262144);     // 81920
    short* Wn1T  = (short*)(ws + 344064);     // 32768
    float* agg   = (float*)(ws + 376832);     // 3145728
    float* u     = (float*)(ws + 3522560);    // 8388608
    float* v     = (float*)(ws + 11911168);   // 8388608

    hipLaunchKernelGGL(prep_kernel, dim3(64), dim3(256), 0, stream,
                       feW0, feW1, feW2, fnW0, fnW1, W1F, W2F, W0uvF, Wn0T, Wn1T);
    hipLaunchKernelGGL(uv_kernel, dim3(128), dim3(256), 0, stream,
                       x, W0uvF, u, v);
    hipLaunchKernelGGL(edge_kernel, dim3(512), dim3(512), 0, stream,
                       x, feW0, feb0, feb1, feb2, W1F, W2F, u, v, agg);
    hipLaunchKernelGGL(node_kernel, dim3(128), dim3(256), 0, stream,
                       x, agg, Wn0T, Wn1T, fnb0, fnb1, (float*)d_out);
}